// Round 1
// baseline (1219.910 us; speedup 1.0000x reference)
//
#include <hip/hip_runtime.h>
#include <hip/hip_bf16.h>
#include <math.h>

typedef __attribute__((ext_vector_type(8))) short short8;
typedef __attribute__((ext_vector_type(4))) float f32x4;
typedef unsigned short ushort_t;
typedef unsigned int uint_t;

#define KCAT 2560
#define VTILES 250

static __device__ __forceinline__ ushort_t f2b(float f){
  __hip_bfloat16 h = __float2bfloat16(f);
  return *reinterpret_cast<ushort_t*>(&h);
}
static __device__ __forceinline__ float b2f(ushort_t u){
  __hip_bfloat16 h = *reinterpret_cast<__hip_bfloat16*>(&u);
  return __bfloat162float(h);
}
static __device__ __forceinline__ float sigmoidf_(float x){ return 1.0f/(1.0f+__expf(-x)); }

// ---------- transpose + f32->bf16 convert: dst[c][dcoloff + r] = src[r][c] ----------
__global__ void k_transpose_cvt(const float* __restrict__ src, ushort_t* __restrict__ dst,
                                int C, int dstride, int dcoloff) {
  __shared__ ushort_t tile[64][72];
  int cb = blockIdx.x * 64, rb = blockIdx.y * 64;
  int tid = threadIdx.x;
  for (int it = 0; it < 4; ++it) {
    int e = tid + it*256;          // 0..1023
    int row = e >> 4;              // 0..63 (source row)
    int seg = e & 15;              // 16 segs of 4 floats
    float4 v = *reinterpret_cast<const float4*>(&src[(size_t)(rb+row)*C + cb + seg*4]);
    tile[seg*4+0][row] = f2b(v.x);
    tile[seg*4+1][row] = f2b(v.y);
    tile[seg*4+2][row] = f2b(v.z);
    tile[seg*4+3][row] = f2b(v.w);
  }
  __syncthreads();
  for (int it = 0; it < 2; ++it) {
    int e = tid + it*256;          // 0..511
    int cl = e >> 3;               // 0..63 (dst row = source col)
    int seg = e & 7;               // 8 segs of 8 ushort
    uint4 v = *reinterpret_cast<uint4*>(&tile[cl][seg*8]);
    *reinterpret_cast<uint4*>(&dst[(size_t)(cb+cl)*dstride + dcoloff + rb + seg*8]) = v;
  }
}

// ---------- embedding gather -> bf16 ----------
__global__ void k_embed(const int* __restrict__ captions, const float* __restrict__ W_embed,
                        ushort_t* __restrict__ xb) {
  int e = (blockIdx.x*256 + threadIdx.x) * 4;   // over 64*32*512
  int nt = e >> 9;
  int n = nt >> 5, t = nt & 31;
  int col = e & 511;
  int tok = captions[n*33 + t];
  float4 v = *reinterpret_cast<const float4*>(&W_embed[(size_t)tok*512 + col]);
  ushort4 o; o.x=f2b(v.x); o.y=f2b(v.y); o.z=f2b(v.z); o.w=f2b(v.w);
  *reinterpret_cast<ushort4*>(&xb[e]) = o;
}

// ---------- A_flat = W_proj^T @ feat + b_proj ; h0 = mean_p ----------
__global__ void k_proj(const float* __restrict__ features, const float* __restrict__ W_proj,
                       const float* __restrict__ b_proj, float* __restrict__ A_flat,
                       float* __restrict__ hbuf, float* __restrict__ cbuf) {
  __shared__ float fLds[16384];
  int kt = blockIdx.x, n = blockIdx.y;
  int tid = threadIdx.x;
  const float* fsrc = features + (size_t)n*16384;
  for (int it = 0; it < 16; ++it) {
    int e = tid + it*256;
    *reinterpret_cast<float4*>(&fLds[e*4]) = *reinterpret_cast<const float4*>(&fsrc[e*4]);
  }
  __syncthreads();
  int k = kt*256 + tid;
  float acc[16];
  #pragma unroll
  for (int p=0;p<16;++p) acc[p]=0.f;
  for (int d = 0; d < 1024; ++d) {
    float w = W_proj[(size_t)d*1024 + k];
    #pragma unroll
    for (int p=0;p<16;++p) acc[p] += fLds[d*16+p]*w;
  }
  float bp = b_proj[k];
  float s = 0.f;
  #pragma unroll
  for (int p=0;p<16;++p){ acc[p]+=bp; s+=acc[p]; }
  float* adst = A_flat + ((size_t)n*1024 + k)*16;
  #pragma unroll
  for (int p=0;p<16;p+=4)
    *reinterpret_cast<float4*>(&adst[p]) = make_float4(acc[p],acc[p+1],acc[p+2],acc[p+3]);
  float h0 = s * (1.f/16.f);
  hbuf[n*1024+k] = h0;
  cbuf[n*1024+k] = h0;
}

// ---------- fused gates (t>0) + attention (t<32) + x-slice copy ----------
__global__ void k_step(int t, const float* __restrict__ a_part, const float* __restrict__ b,
                       const float* __restrict__ A_flat, const float* __restrict__ hbuf,
                       float* __restrict__ cbuf, ushort_t* __restrict__ z,
                       const ushort_t* __restrict__ xb, ushort_t* __restrict__ hall) {
  __shared__ float hLds[1024];
  __shared__ float red[256][17];
  int n = blockIdx.x, tid = threadIdx.x;
  if (t == 0) {
    for (int i=0;i<4;++i){
      int k = tid + 256*i;
      float h = hbuf[n*1024+k];
      hLds[k] = h;
      z[n*KCAT + 512 + k] = f2b(h);
    }
  } else {
    for (int i=0;i<4;++i){
      int k = tid + 256*i;
      float av[4];
      #pragma unroll
      for (int g=0; g<4; ++g){
        int j = g*1024 + k;
        float x = b[j];
        #pragma unroll
        for (int sp=0;sp<4;++sp) x += a_part[(size_t)sp*64*4096 + (size_t)n*4096 + j];
        av[g]=x;
      }
      float ig = sigmoidf_(av[0]);
      float fg = sigmoidf_(av[1]);
      float og = sigmoidf_(av[2]);
      float gg = tanhf(av[3]);
      float c = fg*cbuf[n*1024+k] + ig*gg;
      float h = og*tanhf(c);
      cbuf[n*1024+k] = c;
      hLds[k] = h;
      hall[((size_t)n*32 + (t-1))*1024 + k] = f2b(h);
      if (t < 32) z[n*KCAT + 512 + k] = f2b(h);
    }
  }
  if (t == 32) return;
  __syncthreads();
  // attention scores s[p] = (h . A_flat[n,:,p]) / 32
  float sacc[16];
  #pragma unroll
  for (int p=0;p<16;++p) sacc[p]=0.f;
  const float* An = A_flat + (size_t)n*16384;
  for (int i=0;i<4;++i){
    int k = tid + 256*i;
    float hk = hLds[k];
    #pragma unroll
    for (int p=0;p<16;p+=4){
      float4 av = *reinterpret_cast<const float4*>(&An[k*16+p]);
      sacc[p]   += hk*av.x; sacc[p+1] += hk*av.y;
      sacc[p+2] += hk*av.z; sacc[p+3] += hk*av.w;
    }
  }
  #pragma unroll
  for (int p=0;p<16;++p) red[tid][p] = sacc[p];
  __syncthreads();
  for (int off=128; off>=1; off>>=1){
    if (tid < off){
      #pragma unroll
      for (int p=0;p<16;++p) red[tid][p] += red[tid+off][p];
    }
    __syncthreads();
  }
  float sv[16], wgt[16];
  float m = -1e30f;
  #pragma unroll
  for (int p=0;p<16;++p){ sv[p] = red[0][p]*(1.f/32.f); m = fmaxf(m, sv[p]); }
  float ssum=0.f;
  #pragma unroll
  for (int p=0;p<16;++p){ wgt[p] = __expf(sv[p]-m); ssum += wgt[p]; }
  float inv = 1.f/ssum;
  #pragma unroll
  for (int p=0;p<16;++p) wgt[p]*=inv;
  for (int i=0;i<4;++i){
    int k = tid + 256*i;
    float a_ = 0.f;
    #pragma unroll
    for (int p=0;p<16;p+=4){
      float4 av = *reinterpret_cast<const float4*>(&An[k*16+p]);
      a_ += av.x*wgt[p] + av.y*wgt[p+1] + av.z*wgt[p+2] + av.w*wgt[p+3];
    }
    z[n*KCAT + 512 + 1024 + k] = f2b(a_);
  }
  const ushort_t* xsrc = xb + ((size_t)n*32 + t)*512;
  reinterpret_cast<uint_t*>(&z[n*KCAT])[tid] = reinterpret_cast<const uint_t*>(xsrc)[tid];
}

// ---------- a_part[ks] = z @ Wcat (K-chunk ks), via WcatT rows as MFMA A ----------
__global__ void k_mm(const ushort_t* __restrict__ WcatT, const ushort_t* __restrict__ z,
                     float* __restrict__ a_part) {
  __shared__ ushort_t As[64][72];
  __shared__ ushort_t Zs[64][72];
  __shared__ float Dt[64][68];
  int jt = blockIdx.x, ks = blockIdx.y;
  int tid = threadIdx.x;
  int wave = tid >> 6, lane = tid & 63;
  int lr = lane & 15, lg = lane >> 4;
  int j0 = jt*64;
  f32x4 acc[4];
  #pragma unroll
  for (int i=0;i<4;++i) acc[i] = (f32x4){0.f,0.f,0.f,0.f};
  int kbase = ks*640;
  for (int kc = 0; kc < 640; kc += 64) {
    __syncthreads();
    for (int it=0; it<2; ++it){
      int e = tid + it*256;        // 0..511
      int row = e >> 3, seg = e & 7;
      *reinterpret_cast<uint4*>(&As[row][seg*8]) =
        *reinterpret_cast<const uint4*>(&WcatT[(size_t)(j0+row)*KCAT + kbase+kc + seg*8]);
      *reinterpret_cast<uint4*>(&Zs[row][seg*8]) =
        *reinterpret_cast<const uint4*>(&z[(size_t)row*KCAT + kbase+kc + seg*8]);
    }
    __syncthreads();
    #pragma unroll
    for (int kk=0; kk<64; kk+=32){
      short8 af = *reinterpret_cast<short8*>(&As[wave*16 + lr][kk + lg*8]);
      #pragma unroll
      for (int nf=0; nf<4; ++nf){
        short8 bf = *reinterpret_cast<short8*>(&Zs[nf*16 + lr][kk + lg*8]);
        acc[nf] = __builtin_amdgcn_mfma_f32_16x16x32_bf16(af, bf, acc[nf], 0, 0, 0);
      }
    }
  }
  __syncthreads();
  #pragma unroll
  for (int nf=0; nf<4; ++nf)
    #pragma unroll
    for (int r=0;r<4;++r)
      Dt[nf*16+lr][wave*16 + lg*4 + r] = acc[nf][r];
  __syncthreads();
  for (int it=0; it<4; ++it){
    int e = tid + it*256;          // 0..1023
    int nrow = e >> 4, seg = e & 15;
    float4 v = *reinterpret_cast<float4*>(&Dt[nrow][seg*4]);
    *reinterpret_cast<float4*>(&a_part[(size_t)ks*64*4096 + (size_t)nrow*4096 + j0 + seg*4]) = v;
  }
}

// ---------- scores tile + fused partial logsumexp over 128-v tile ----------
__global__ void k_score(const ushort_t* __restrict__ WoutT, const ushort_t* __restrict__ hall,
                        const float* __restrict__ b_out,
                        float* __restrict__ pmax, float* __restrict__ psum) {
  __shared__ ushort_t As[128][72];
  __shared__ ushort_t Bs[128][72];
  __shared__ float bLds[128];
  __shared__ float pmLds[4][128];
  __shared__ float psLds[4][128];
  int vb = blockIdx.x, rb = blockIdx.y;
  int v0 = vb*128, r0 = rb*128;
  int tid = threadIdx.x;
  int wave = tid>>6, lane = tid&63, lr = lane&15, lg = lane>>4;
  if (tid < 128) bLds[tid] = b_out[v0 + tid];
  f32x4 acc[2][8];
  #pragma unroll
  for (int a=0;a<2;++a)
    #pragma unroll
    for (int q=0;q<8;++q) acc[a][q]=(f32x4){0.f,0.f,0.f,0.f};
  for (int kc=0; kc<1024; kc+=64){
    __syncthreads();
    for (int it=0; it<4; ++it){
      int e = tid + it*256;        // 0..1023
      int row = e>>3, seg = e&7;
      *reinterpret_cast<uint4*>(&As[row][seg*8]) =
        *reinterpret_cast<const uint4*>(&WoutT[(size_t)(v0+row)*1024 + kc + seg*8]);
      *reinterpret_cast<uint4*>(&Bs[row][seg*8]) =
        *reinterpret_cast<const uint4*>(&hall[(size_t)(r0+row)*1024 + kc + seg*8]);
    }
    __syncthreads();
    #pragma unroll
    for (int kk=0;kk<64;kk+=32){
      short8 af0 = *reinterpret_cast<short8*>(&As[wave*32 + lr][kk+lg*8]);
      short8 af1 = *reinterpret_cast<short8*>(&As[wave*32 + 16 + lr][kk+lg*8]);
      #pragma unroll
      for (int nr=0;nr<8;++nr){
        short8 bf = *reinterpret_cast<short8*>(&Bs[nr*16+lr][kk+lg*8]);
        acc[0][nr] = __builtin_amdgcn_mfma_f32_16x16x32_bf16(af0, bf, acc[0][nr], 0,0,0);
        acc[1][nr] = __builtin_amdgcn_mfma_f32_16x16x32_bf16(af1, bf, acc[1][nr], 0,0,0);
      }
    }
  }
  #pragma unroll
  for (int nr=0;nr<8;++nr){
    float m = -1e30f;
    float xv[8];
    #pragma unroll
    for (int mv=0;mv<2;++mv)
      #pragma unroll
      for (int r=0;r<4;++r){
        float x = acc[mv][nr][r] + bLds[wave*32 + mv*16 + lg*4 + r];
        xv[mv*4+r]=x; m = fmaxf(m,x);
      }
    float s=0.f;
    #pragma unroll
    for (int i=0;i<8;++i) s += __expf(xv[i]-m);
    #pragma unroll
    for (int d=16; d<=32; d<<=1){
      float om = __shfl_xor(m, d, 64);
      float os = __shfl_xor(s, d, 64);
      float nm = fmaxf(m, om);
      s = s*__expf(m-nm) + os*__expf(om-nm);
      m = nm;
    }
    if (lg == 0){
      pmLds[wave][nr*16+lr] = m;
      psLds[wave][nr*16+lr] = s;
    }
  }
  __syncthreads();
  if (tid < 128){
    float m=-1e30f;
    #pragma unroll
    for (int w=0;w<4;++w) m = fmaxf(m, pmLds[w][tid]);
    float s=0.f;
    #pragma unroll
    for (int w=0;w<4;++w) s += psLds[w][tid]*__expf(pmLds[w][tid]-m);
    pmax[(size_t)(r0+tid)*VTILES + vb] = m;
    psum[(size_t)(r0+tid)*VTILES + vb] = s;
  }
}

// ---------- target scores ----------
__global__ void k_tgt(const ushort_t* __restrict__ hall, const ushort_t* __restrict__ WoutT,
                      const float* __restrict__ b_out, const int* __restrict__ captions,
                      float* __restrict__ stgt) {
  int tid = threadIdx.x;
  int wave = tid>>6, lane = tid&63;
  int r = blockIdx.x*4 + wave;
  int n = r>>5, t = r&31;
  int y = captions[n*33 + t + 1];
  const ushort_t* hrow = hall + (size_t)r*1024;
  const ushort_t* wrow = WoutT + (size_t)y*1024;
  float dot = 0.f;
  #pragma unroll
  for (int i=0;i<2;++i){
    int off = lane*8 + i*512;
    short8 hv = *reinterpret_cast<const short8*>(&hrow[off]);
    short8 wv = *reinterpret_cast<const short8*>(&wrow[off]);
    #pragma unroll
    for (int e2=0;e2<8;++e2) dot += b2f((ushort_t)hv[e2])*b2f((ushort_t)wv[e2]);
  }
  #pragma unroll
  for (int d=32; d>=1; d>>=1) dot += __shfl_xor(dot, d, 64);
  if (lane==0) stgt[r] = dot + b_out[y];
}

// ---------- combine partials -> per-row masked nll ----------
__global__ void k_reduce(const float* __restrict__ pmax, const float* __restrict__ psum,
                         const float* __restrict__ stgt, const int* __restrict__ captions,
                         float* __restrict__ row_loss) {
  int tid = threadIdx.x;
  int wave = tid>>6, lane = tid&63;
  int r = blockIdx.x*4 + wave;
  float m = -1e30f, s = 0.f;
  for (int j = lane; j < VTILES; j += 64){
    float mj = pmax[(size_t)r*VTILES + j];
    float sj = psum[(size_t)r*VTILES + j];
    float nm = fmaxf(m, mj);
    s = s*__expf(m-nm) + sj*__expf(mj-nm);
    m = nm;
  }
  #pragma unroll
  for (int d=32; d>=1; d>>=1){
    float om = __shfl_xor(m, d, 64);
    float os = __shfl_xor(s, d, 64);
    float nm = fmaxf(m, om);
    s = s*__expf(m-nm) + os*__expf(om-nm);
    m = nm;
  }
  if (lane==0){
    int n = r>>5, t = r&31;
    int y = captions[n*33 + t + 1];
    float lse = m + __logf(s);
    row_loss[r] = (y != 0) ? (lse - stgt[r]) : 0.f;
  }
}

// ---------- final deterministic sum ----------
__global__ void k_final(const float* __restrict__ row_loss, float* __restrict__ out) {
  __shared__ float red[256];
  int tid = threadIdx.x;
  float s = 0.f;
  #pragma unroll
  for (int i=0;i<8;++i) s += row_loss[tid + i*256];
  red[tid] = s;
  __syncthreads();
  for (int off=128; off>=1; off>>=1){
    if (tid<off) red[tid] += red[tid+off];
    __syncthreads();
  }
  if (tid==0) out[0] = red[0] * (1.f/64.f);
}

extern "C" void kernel_launch(void* const* d_in, const int* in_sizes, int n_in,
                              void* d_out, int out_size, void* d_ws, size_t ws_size,
                              hipStream_t stream) {
  const float* features = (const float*)d_in[0];
  const int*   captions = (const int*)d_in[1];
  const float* W_embed  = (const float*)d_in[2];
  const float* Wx       = (const float*)d_in[3];
  const float* Wh       = (const float*)d_in[4];
  const float* Wattn    = (const float*)d_in[5];
  const float* b        = (const float*)d_in[6];
  const float* W_proj   = (const float*)d_in[7];
  const float* b_proj   = (const float*)d_in[8];
  const float* W_out    = (const float*)d_in[9];
  const float* b_out    = (const float*)d_in[10];
  float* out = (float*)d_out;

  char* wsp = (char*)d_ws;
  size_t off = 0;
  auto alloc = [&](size_t bytes)->char*{
    char* p = wsp + off; off += (bytes + 255) & ~(size_t)255; return p;
  };
  ushort_t* WcatT = (ushort_t*)alloc((size_t)4096*2560*2);
  ushort_t* WoutT = (ushort_t*)alloc((size_t)32000*1024*2);
  float* A_flat   = (float*)alloc((size_t)64*1024*16*4);
  ushort_t* xb    = (ushort_t*)alloc((size_t)64*32*512*2);
  float* hbuf     = (float*)alloc((size_t)64*1024*4);
  float* cbuf     = (float*)alloc((size_t)64*1024*4);
  ushort_t* z     = (ushort_t*)alloc((size_t)64*2560*2);
  float* a_part   = (float*)alloc((size_t)4*64*4096*4);
  ushort_t* hall  = (ushort_t*)alloc((size_t)2048*1024*2);
  float* pmax     = (float*)alloc((size_t)2048*250*4);
  float* psum     = (float*)alloc((size_t)2048*250*4);
  float* stgt     = (float*)alloc((size_t)2048*4);
  float* row_loss = (float*)alloc((size_t)2048*4);

  hipLaunchKernelGGL(k_transpose_cvt, dim3(64, 8),   dim3(256), 0, stream, Wx,    WcatT, 4096, 2560, 0);
  hipLaunchKernelGGL(k_transpose_cvt, dim3(64, 16),  dim3(256), 0, stream, Wh,    WcatT, 4096, 2560, 512);
  hipLaunchKernelGGL(k_transpose_cvt, dim3(64, 16),  dim3(256), 0, stream, Wattn, WcatT, 4096, 2560, 1536);
  hipLaunchKernelGGL(k_transpose_cvt, dim3(500, 16), dim3(256), 0, stream, W_out, WoutT, 32000, 1024, 0);
  hipLaunchKernelGGL(k_embed, dim3(1024), dim3(256), 0, stream, captions, W_embed, xb);
  hipLaunchKernelGGL(k_proj, dim3(4, 64), dim3(256), 0, stream, features, W_proj, b_proj, A_flat, hbuf, cbuf);

  for (int t = 0; t < 32; ++t){
    hipLaunchKernelGGL(k_step, dim3(64), dim3(256), 0, stream, t, a_part, b, A_flat, hbuf, cbuf, z, xb, hall);
    hipLaunchKernelGGL(k_mm, dim3(64, 4), dim3(256), 0, stream, WcatT, z, a_part);
  }
  hipLaunchKernelGGL(k_step, dim3(64), dim3(256), 0, stream, 32, a_part, b, A_flat, hbuf, cbuf, z, xb, hall);

  hipLaunchKernelGGL(k_score, dim3(250, 16), dim3(256), 0, stream, WoutT, hall, b_out, pmax, psum);
  hipLaunchKernelGGL(k_tgt, dim3(512), dim3(256), 0, stream, hall, WoutT, b_out, captions, stgt);
  hipLaunchKernelGGL(k_reduce, dim3(512), dim3(256), 0, stream, pmax, psum, stgt, captions, row_loss);
  hipLaunchKernelGGL(k_final, dim3(1), dim3(256), 0, stream, row_loss, out);
}

// Round 2
// 1029.514 us; speedup vs baseline: 1.1849x; 1.1849x over previous
//
#include <hip/hip_runtime.h>
#include <hip/hip_bf16.h>
#include <math.h>

typedef __attribute__((ext_vector_type(8))) short short8;
typedef __attribute__((ext_vector_type(4))) float f32x4;
typedef unsigned short ushort_t;
typedef unsigned int uint_t;

typedef __attribute__((address_space(1))) const void gvoid_t;
typedef __attribute__((address_space(3))) void lvoid_t;

#define KCAT 2560
#define VTILES 250

static __device__ __forceinline__ ushort_t f2b(float f){
  __hip_bfloat16 h = __float2bfloat16(f);
  return *reinterpret_cast<ushort_t*>(&h);
}
static __device__ __forceinline__ float b2f(ushort_t u){
  __hip_bfloat16 h = *reinterpret_cast<__hip_bfloat16*>(&u);
  return __bfloat162float(h);
}
static __device__ __forceinline__ float sigmoidf_(float x){ return 1.0f/(1.0f+__expf(-x)); }

// ---------- transpose + f32->bf16 convert: dst[c][dcoloff + r] = src[r][c] ----------
__global__ void k_transpose_cvt(const float* __restrict__ src, ushort_t* __restrict__ dst,
                                int C, int dstride, int dcoloff) {
  __shared__ ushort_t tile[64][72];
  int cb = blockIdx.x * 64, rb = blockIdx.y * 64;
  int tid = threadIdx.x;
  for (int it = 0; it < 4; ++it) {
    int e = tid + it*256;          // 0..1023
    int row = e >> 4;              // 0..63 (source row)
    int seg = e & 15;              // 16 segs of 4 floats
    float4 v = *reinterpret_cast<const float4*>(&src[(size_t)(rb+row)*C + cb + seg*4]);
    tile[seg*4+0][row] = f2b(v.x);
    tile[seg*4+1][row] = f2b(v.y);
    tile[seg*4+2][row] = f2b(v.z);
    tile[seg*4+3][row] = f2b(v.w);
  }
  __syncthreads();
  for (int it = 0; it < 2; ++it) {
    int e = tid + it*256;          // 0..511
    int cl = e >> 3;               // 0..63 (dst row = source col)
    int seg = e & 7;               // 8 segs of 8 ushort
    uint4 v = *reinterpret_cast<uint4*>(&tile[cl][seg*8]);
    *reinterpret_cast<uint4*>(&dst[(size_t)(cb+cl)*dstride + dcoloff + rb + seg*8]) = v;
  }
}

// ---------- embedding gather -> bf16 ----------
__global__ void k_embed(const int* __restrict__ captions, const float* __restrict__ W_embed,
                        ushort_t* __restrict__ xb) {
  int e = (blockIdx.x*256 + threadIdx.x) * 4;   // over 64*32*512
  int nt = e >> 9;
  int n = nt >> 5, t = nt & 31;
  int col = e & 511;
  int tok = captions[n*33 + t];
  float4 v = *reinterpret_cast<const float4*>(&W_embed[(size_t)tok*512 + col]);
  ushort4 o; o.x=f2b(v.x); o.y=f2b(v.y); o.z=f2b(v.z); o.w=f2b(v.w);
  *reinterpret_cast<ushort4*>(&xb[e]) = o;
}

// ---------- A_flat = W_proj^T @ feat + b_proj ; h0 = mean_p ----------
__global__ void k_proj(const float* __restrict__ features, const float* __restrict__ W_proj,
                       const float* __restrict__ b_proj, float* __restrict__ A_flat,
                       float* __restrict__ hbuf, float* __restrict__ cbuf) {
  __shared__ float fLds[16384];
  int kt = blockIdx.x, n = blockIdx.y;
  int tid = threadIdx.x;
  const float* fsrc = features + (size_t)n*16384;
  for (int it = 0; it < 16; ++it) {
    int e = tid + it*256;
    *reinterpret_cast<float4*>(&fLds[e*4]) = *reinterpret_cast<const float4*>(&fsrc[e*4]);
  }
  __syncthreads();
  int k = kt*256 + tid;
  float acc[16];
  #pragma unroll
  for (int p=0;p<16;++p) acc[p]=0.f;
  for (int d = 0; d < 1024; ++d) {
    float w = W_proj[(size_t)d*1024 + k];
    #pragma unroll
    for (int p=0;p<16;++p) acc[p] += fLds[d*16+p]*w;
  }
  float bp = b_proj[k];
  float s = 0.f;
  #pragma unroll
  for (int p=0;p<16;++p){ acc[p]+=bp; s+=acc[p]; }
  float* adst = A_flat + ((size_t)n*1024 + k)*16;
  #pragma unroll
  for (int p=0;p<16;p+=4)
    *reinterpret_cast<float4*>(&adst[p]) = make_float4(acc[p],acc[p+1],acc[p+2],acc[p+3]);
  float h0 = s * (1.f/16.f);
  hbuf[n*1024+k] = h0;
  cbuf[n*1024+k] = h0;
}

// ---------- fused gates (t>0) + attention (t<32) + x-slice copy ----------
__global__ void k_step(int t, const float* __restrict__ a_part, const float* __restrict__ b,
                       const float* __restrict__ A_flat, const float* __restrict__ hbuf,
                       float* __restrict__ cbuf, ushort_t* __restrict__ z,
                       const ushort_t* __restrict__ xb, ushort_t* __restrict__ hall) {
  __shared__ float hLds[1024];
  __shared__ float red[256][17];
  int n = blockIdx.x, tid = threadIdx.x;
  if (t == 0) {
    for (int i=0;i<4;++i){
      int k = tid + 256*i;
      float h = hbuf[n*1024+k];
      hLds[k] = h;
      z[n*KCAT + 512 + k] = f2b(h);
    }
  } else {
    for (int i=0;i<4;++i){
      int k = tid + 256*i;
      float av[4];
      #pragma unroll
      for (int g=0; g<4; ++g){
        int j = g*1024 + k;
        float x = b[j];
        #pragma unroll
        for (int sp=0;sp<4;++sp) x += a_part[(size_t)sp*64*4096 + (size_t)n*4096 + j];
        av[g]=x;
      }
      float ig = sigmoidf_(av[0]);
      float fg = sigmoidf_(av[1]);
      float og = sigmoidf_(av[2]);
      float gg = tanhf(av[3]);
      float c = fg*cbuf[n*1024+k] + ig*gg;
      float h = og*tanhf(c);
      cbuf[n*1024+k] = c;
      hLds[k] = h;
      hall[((size_t)n*32 + (t-1))*1024 + k] = f2b(h);
      if (t < 32) z[n*KCAT + 512 + k] = f2b(h);
    }
  }
  if (t == 32) return;
  __syncthreads();
  // attention scores s[p] = (h . A_flat[n,:,p]) / 32
  float sacc[16];
  #pragma unroll
  for (int p=0;p<16;++p) sacc[p]=0.f;
  const float* An = A_flat + (size_t)n*16384;
  for (int i=0;i<4;++i){
    int k = tid + 256*i;
    float hk = hLds[k];
    #pragma unroll
    for (int p=0;p<16;p+=4){
      float4 av = *reinterpret_cast<const float4*>(&An[k*16+p]);
      sacc[p]   += hk*av.x; sacc[p+1] += hk*av.y;
      sacc[p+2] += hk*av.z; sacc[p+3] += hk*av.w;
    }
  }
  #pragma unroll
  for (int p=0;p<16;++p) red[tid][p] = sacc[p];
  __syncthreads();
  for (int off=128; off>=1; off>>=1){
    if (tid < off){
      #pragma unroll
      for (int p=0;p<16;++p) red[tid][p] += red[tid+off][p];
    }
    __syncthreads();
  }
  float sv[16], wgt[16];
  float m = -1e30f;
  #pragma unroll
  for (int p=0;p<16;++p){ sv[p] = red[0][p]*(1.f/32.f); m = fmaxf(m, sv[p]); }
  float ssum=0.f;
  #pragma unroll
  for (int p=0;p<16;++p){ wgt[p] = __expf(sv[p]-m); ssum += wgt[p]; }
  float inv = 1.f/ssum;
  #pragma unroll
  for (int p=0;p<16;++p) wgt[p]*=inv;
  for (int i=0;i<4;++i){
    int k = tid + 256*i;
    float a_ = 0.f;
    #pragma unroll
    for (int p=0;p<16;p+=4){
      float4 av = *reinterpret_cast<const float4*>(&An[k*16+p]);
      a_ += av.x*wgt[p] + av.y*wgt[p+1] + av.z*wgt[p+2] + av.w*wgt[p+3];
    }
    z[n*KCAT + 512 + 1024 + k] = f2b(a_);
  }
  const ushort_t* xsrc = xb + ((size_t)n*32 + t)*512;
  reinterpret_cast<uint_t*>(&z[n*KCAT])[tid] = reinterpret_cast<const uint_t*>(xsrc)[tid];
}

// ---------- a_part[ks] = z @ Wcat (K-chunk ks), via WcatT rows as MFMA A ----------
__global__ void k_mm(const ushort_t* __restrict__ WcatT, const ushort_t* __restrict__ z,
                     float* __restrict__ a_part) {
  __shared__ ushort_t As[64][72];
  __shared__ ushort_t Zs[64][72];
  __shared__ float Dt[64][68];
  int jt = blockIdx.x, ks = blockIdx.y;
  int tid = threadIdx.x;
  int wave = tid >> 6, lane = tid & 63;
  int lr = lane & 15, lg = lane >> 4;
  int j0 = jt*64;
  f32x4 acc[4];
  #pragma unroll
  for (int i=0;i<4;++i) acc[i] = (f32x4){0.f,0.f,0.f,0.f};
  int kbase = ks*640;
  for (int kc = 0; kc < 640; kc += 64) {
    __syncthreads();
    for (int it=0; it<2; ++it){
      int e = tid + it*256;        // 0..511
      int row = e >> 3, seg = e & 7;
      *reinterpret_cast<uint4*>(&As[row][seg*8]) =
        *reinterpret_cast<const uint4*>(&WcatT[(size_t)(j0+row)*KCAT + kbase+kc + seg*8]);
      *reinterpret_cast<uint4*>(&Zs[row][seg*8]) =
        *reinterpret_cast<const uint4*>(&z[(size_t)row*KCAT + kbase+kc + seg*8]);
    }
    __syncthreads();
    #pragma unroll
    for (int kk=0; kk<64; kk+=32){
      short8 af = *reinterpret_cast<short8*>(&As[wave*16 + lr][kk + lg*8]);
      #pragma unroll
      for (int nf=0; nf<4; ++nf){
        short8 bf = *reinterpret_cast<short8*>(&Zs[nf*16 + lr][kk + lg*8]);
        acc[nf] = __builtin_amdgcn_mfma_f32_16x16x32_bf16(af, bf, acc[nf], 0, 0, 0);
      }
    }
  }
  __syncthreads();
  #pragma unroll
  for (int nf=0; nf<4; ++nf)
    #pragma unroll
    for (int r=0;r<4;++r)
      Dt[nf*16+lr][wave*16 + lg*4 + r] = acc[nf][r];
  __syncthreads();
  for (int it=0; it<4; ++it){
    int e = tid + it*256;          // 0..1023
    int nrow = e >> 4, seg = e & 15;
    float4 v = *reinterpret_cast<float4*>(&Dt[nrow][seg*4]);
    *reinterpret_cast<float4*>(&a_part[(size_t)ks*64*4096 + (size_t)nrow*4096 + j0 + seg*4]) = v;
  }
}

// ---------- scores tile + fused partial logsumexp over 128-v tile ----------
// global_load_lds staging, XOR-swizzled source (rule #21), XCD-aware grid.
__global__ void __launch_bounds__(256, 4)
k_score(const ushort_t* __restrict__ WoutT, const ushort_t* __restrict__ hall,
        const float* __restrict__ b_out,
        float* __restrict__ pmax, float* __restrict__ psum) {
  __shared__ ushort_t As[128*64];
  __shared__ ushort_t Bs[128*64];
  __shared__ float bLds[128];
  __shared__ float pmLds[4][128];
  __shared__ float psLds[4][128];
  int bid = blockIdx.x;
  // bijective XCD swizzle: 4000 wgs = 8 XCDs x 500; each XCD owns a
  // contiguous vb-major chunk so WoutT tiles are fetched once per XCD.
  int wg = (bid & 7) * 500 + (bid >> 3);
  int vb = wg >> 4, rb = wg & 15;
  int v0 = vb * 128, r0 = rb * 128;
  int tid = threadIdx.x;
  int wave = tid >> 6, lane = tid & 63, lr = lane & 15, lg = lane >> 4;
  if (tid < 128) bLds[tid] = b_out[v0 + tid];

  // staging geometry: per wave 4 chunks of 1KB per matrix; lane covers
  // (row = chunkrow + lane>>3, seg' = lane&7); source col pre-XOR'd so the
  // linear LDS write lands swizzled: col16 = (lane&7) ^ (lane>>3).
  int srow = lane >> 3;
  int sxor = ((lane & 7) ^ srow) << 3;     // element offset within 64-col chunk

  f32x4 acc[2][8];
  #pragma unroll
  for (int a=0;a<2;++a)
    #pragma unroll
    for (int q=0;q<8;++q) acc[a][q]=(f32x4){0.f,0.f,0.f,0.f};

  for (int kc = 0; kc < 1024; kc += 64) {
    __syncthreads();   // previous tile's ds_reads complete before overwrite
    #pragma unroll
    for (int i = 0; i < 4; ++i) {
      int rowg = (wave*4 + i) * 8;
      const ushort_t* gsA = &WoutT[(size_t)(v0 + rowg + srow)*1024 + kc + sxor];
      const ushort_t* gsB = &hall [(size_t)(r0 + rowg + srow)*1024 + kc + sxor];
      __builtin_amdgcn_global_load_lds((gvoid_t*)gsA, (lvoid_t*)&As[rowg*64], 16, 0, 0);
      __builtin_amdgcn_global_load_lds((gvoid_t*)gsB, (lvoid_t*)&Bs[rowg*64], 16, 0, 0);
    }
    __syncthreads();   // vmcnt(0) drain: tile ready
    #pragma unroll
    for (int kk = 0; kk < 2; ++kk) {
      int swz = ((kk*4 + lg) ^ (lr & 7)) << 3;
      int rowA = wave*32 + lr;
      short8 af0 = *reinterpret_cast<short8*>(&As[rowA*64 + swz]);
      short8 af1 = *reinterpret_cast<short8*>(&As[(rowA+16)*64 + swz]);
      #pragma unroll
      for (int nr = 0; nr < 8; ++nr) {
        short8 bf = *reinterpret_cast<short8*>(&Bs[(nr*16+lr)*64 + swz]);
        acc[0][nr] = __builtin_amdgcn_mfma_f32_16x16x32_bf16(af0, bf, acc[0][nr], 0,0,0);
        acc[1][nr] = __builtin_amdgcn_mfma_f32_16x16x32_bf16(af1, bf, acc[1][nr], 0,0,0);
      }
    }
  }
  #pragma unroll
  for (int nr=0;nr<8;++nr){
    float m = -1e30f;
    float xv[8];
    #pragma unroll
    for (int mv=0;mv<2;++mv)
      #pragma unroll
      for (int r=0;r<4;++r){
        float x = acc[mv][nr][r] + bLds[wave*32 + mv*16 + lg*4 + r];
        xv[mv*4+r]=x; m = fmaxf(m,x);
      }
    float s=0.f;
    #pragma unroll
    for (int i=0;i<8;++i) s += __expf(xv[i]-m);
    #pragma unroll
    for (int d=16; d<=32; d<<=1){
      float om = __shfl_xor(m, d, 64);
      float os = __shfl_xor(s, d, 64);
      float nm = fmaxf(m, om);
      s = s*__expf(m-nm) + os*__expf(om-nm);
      m = nm;
    }
    if (lg == 0){
      pmLds[wave][nr*16+lr] = m;
      psLds[wave][nr*16+lr] = s;
    }
  }
  __syncthreads();
  if (tid < 128){
    float m=-1e30f;
    #pragma unroll
    for (int w=0;w<4;++w) m = fmaxf(m, pmLds[w][tid]);
    float s=0.f;
    #pragma unroll
    for (int w=0;w<4;++w) s += psLds[w][tid]*__expf(pmLds[w][tid]-m);
    pmax[(size_t)(r0+tid)*VTILES + vb] = m;
    psum[(size_t)(r0+tid)*VTILES + vb] = s;
  }
}

// ---------- target scores ----------
__global__ void k_tgt(const ushort_t* __restrict__ hall, const ushort_t* __restrict__ WoutT,
                      const float* __restrict__ b_out, const int* __restrict__ captions,
                      float* __restrict__ stgt) {
  int tid = threadIdx.x;
  int wave = tid>>6, lane = tid&63;
  int r = blockIdx.x*4 + wave;
  int n = r>>5, t = r&31;
  int y = captions[n*33 + t + 1];
  const ushort_t* hrow = hall + (size_t)r*1024;
  const ushort_t* wrow = WoutT + (size_t)y*1024;
  float dot = 0.f;
  #pragma unroll
  for (int i=0;i<2;++i){
    int off = lane*8 + i*512;
    short8 hv = *reinterpret_cast<const short8*>(&hrow[off]);
    short8 wv = *reinterpret_cast<const short8*>(&wrow[off]);
    #pragma unroll
    for (int e2=0;e2<8;++e2) dot += b2f((ushort_t)hv[e2])*b2f((ushort_t)wv[e2]);
  }
  #pragma unroll
  for (int d=32; d>=1; d>>=1) dot += __shfl_xor(dot, d, 64);
  if (lane==0) stgt[r] = dot + b_out[y];
}

// ---------- combine partials -> per-row masked nll ----------
__global__ void k_reduce(const float* __restrict__ pmax, const float* __restrict__ psum,
                         const float* __restrict__ stgt, const int* __restrict__ captions,
                         float* __restrict__ row_loss) {
  int tid = threadIdx.x;
  int wave = tid>>6, lane = tid&63;
  int r = blockIdx.x*4 + wave;
  float m = -1e30f, s = 0.f;
  for (int j = lane; j < VTILES; j += 64){
    float mj = pmax[(size_t)r*VTILES + j];
    float sj = psum[(size_t)r*VTILES + j];
    float nm = fmaxf(m, mj);
    s = s*__expf(m-nm) + sj*__expf(mj-nm);
    m = nm;
  }
  #pragma unroll
  for (int d=32; d>=1; d>>=1){
    float om = __shfl_xor(m, d, 64);
    float os = __shfl_xor(s, d, 64);
    float nm = fmaxf(m, om);
    s = s*__expf(m-nm) + os*__expf(om-nm);
    m = nm;
  }
  if (lane==0){
    int n = r>>5, t = r&31;
    int y = captions[n*33 + t + 1];
    float lse = m + __logf(s);
    row_loss[r] = (y != 0) ? (lse - stgt[r]) : 0.f;
  }
}

// ---------- final deterministic sum ----------
__global__ void k_final(const float* __restrict__ row_loss, float* __restrict__ out) {
  __shared__ float red[256];
  int tid = threadIdx.x;
  float s = 0.f;
  #pragma unroll
  for (int i=0;i<8;++i) s += row_loss[tid + i*256];
  red[tid] = s;
  __syncthreads();
  for (int off=128; off>=1; off>>=1){
    if (tid<off) red[tid] += red[tid+off];
    __syncthreads();
  }
  if (tid==0) out[0] = red[0] * (1.f/64.f);
}

extern "C" void kernel_launch(void* const* d_in, const int* in_sizes, int n_in,
                              void* d_out, int out_size, void* d_ws, size_t ws_size,
                              hipStream_t stream) {
  const float* features = (const float*)d_in[0];
  const int*   captions = (const int*)d_in[1];
  const float* W_embed  = (const float*)d_in[2];
  const float* Wx       = (const float*)d_in[3];
  const float* Wh       = (const float*)d_in[4];
  const float* Wattn    = (const float*)d_in[5];
  const float* b        = (const float*)d_in[6];
  const float* W_proj   = (const float*)d_in[7];
  const float* b_proj   = (const float*)d_in[8];
  const float* W_out    = (const float*)d_in[9];
  const float* b_out    = (const float*)d_in[10];
  float* out = (float*)d_out;

  char* wsp = (char*)d_ws;
  size_t off = 0;
  auto alloc = [&](size_t bytes)->char*{
    char* p = wsp + off; off += (bytes + 255) & ~(size_t)255; return p;
  };
  ushort_t* WcatT = (ushort_t*)alloc((size_t)4096*2560*2);
  ushort_t* WoutT = (ushort_t*)alloc((size_t)32000*1024*2);
  float* A_flat   = (float*)alloc((size_t)64*1024*16*4);
  ushort_t* xb    = (ushort_t*)alloc((size_t)64*32*512*2);
  float* hbuf     = (float*)alloc((size_t)64*1024*4);
  float* cbuf     = (float*)alloc((size_t)64*1024*4);
  ushort_t* z     = (ushort_t*)alloc((size_t)64*2560*2);
  float* a_part   = (float*)alloc((size_t)4*64*4096*4);
  ushort_t* hall  = (ushort_t*)alloc((size_t)2048*1024*2);
  float* pmax     = (float*)alloc((size_t)2048*250*4);
  float* psum     = (float*)alloc((size_t)2048*250*4);
  float* stgt     = (float*)alloc((size_t)2048*4);
  float* row_loss = (float*)alloc((size_t)2048*4);

  hipLaunchKernelGGL(k_transpose_cvt, dim3(64, 8),   dim3(256), 0, stream, Wx,    WcatT, 4096, 2560, 0);
  hipLaunchKernelGGL(k_transpose_cvt, dim3(64, 16),  dim3(256), 0, stream, Wh,    WcatT, 4096, 2560, 512);
  hipLaunchKernelGGL(k_transpose_cvt, dim3(64, 16),  dim3(256), 0, stream, Wattn, WcatT, 4096, 2560, 1536);
  hipLaunchKernelGGL(k_transpose_cvt, dim3(500, 16), dim3(256), 0, stream, W_out, WoutT, 32000, 1024, 0);
  hipLaunchKernelGGL(k_embed, dim3(1024), dim3(256), 0, stream, captions, W_embed, xb);
  hipLaunchKernelGGL(k_proj, dim3(4, 64), dim3(256), 0, stream, features, W_proj, b_proj, A_flat, hbuf, cbuf);

  for (int t = 0; t < 32; ++t){
    hipLaunchKernelGGL(k_step, dim3(64), dim3(256), 0, stream, t, a_part, b, A_flat, hbuf, cbuf, z, xb, hall);
    hipLaunchKernelGGL(k_mm, dim3(64, 4), dim3(256), 0, stream, WcatT, z, a_part);
  }
  hipLaunchKernelGGL(k_step, dim3(64), dim3(256), 0, stream, 32, a_part, b, A_flat, hbuf, cbuf, z, xb, hall);

  hipLaunchKernelGGL(k_score, dim3(4000), dim3(256), 0, stream, WoutT, hall, b_out, pmax, psum);
  hipLaunchKernelGGL(k_tgt, dim3(512), dim3(256), 0, stream, hall, WoutT, b_out, captions, stgt);
  hipLaunchKernelGGL(k_reduce, dim3(512), dim3(256), 0, stream, pmax, psum, stgt, captions, row_loss);
  hipLaunchKernelGGL(k_final, dim3(1), dim3(256), 0, stream, row_loss, out);
}